// Round 1
// baseline (299.567 us; speedup 1.0000x reference)
//
#include <hip/hip_runtime.h>
#include <hip/hip_bf16.h>
#include <stdint.h>

#define S_LEN 2048
#define DIMSZ 2048
#define NH    16
#define HD    128
#define NQK   2176   // Q cols (2048) + K cols (128); V cols start here
#define NQKV  2304

typedef short  bf16x8  __attribute__((ext_vector_type(8)));
typedef float  floatx4 __attribute__((ext_vector_type(4)));
typedef unsigned short u16;

// round-to-nearest-even f32 -> bf16 bits
__device__ __forceinline__ u16 f2bf(float x) {
  unsigned int u = __builtin_bit_cast(unsigned int, x);
  u = (u + 0x7FFFu + ((u >> 16) & 1u)) >> 16;
  return (u16)u;
}

// async global->LDS, 16 bytes per lane; LDS dest must be wave-uniform base (+lane*16 by HW)
__device__ __forceinline__ void gload16(const void* g, void* l) {
  __builtin_amdgcn_global_load_lds(
      reinterpret_cast<const __attribute__((address_space(1))) void*>(reinterpret_cast<uintptr_t>(g)),
      reinterpret_cast<__attribute__((address_space(3))) void*>(reinterpret_cast<uintptr_t>(l)),
      16, 0, 0);
}

// ---------------- converts ----------------
__global__ void k_cvt_bf16(const float* __restrict__ in, u16* __restrict__ out, int n4) {
  int i = blockIdx.x * blockDim.x + threadIdx.x;
  if (i < n4) {
    float4 v = ((const float4*)in)[i];
    ushort4 o;
    o.x = f2bf(v.x); o.y = f2bf(v.y); o.z = f2bf(v.z); o.w = f2bf(v.w);
    ((ushort4*)out)[i] = o;
  }
}

// in: (K x N) f32 row-major  ->  out rows [rowOff .. rowOff+N): (N x K) bf16
__global__ void k_transpose_bf16(const float* __restrict__ in, u16* __restrict__ out,
                                 int K, int N, int rowOff) {
  __shared__ float t[64][65];
  int c0 = blockIdx.x * 64;   // N dim
  int r0 = blockIdx.y * 64;   // K dim
  int tid = threadIdx.x;
  int lr = tid >> 6;          // 0..3
  int lc = tid & 63;
#pragma unroll
  for (int i = 0; i < 16; ++i) {
    int r = lr + i * 4;
    t[r][lc] = in[(size_t)(r0 + r) * N + c0 + lc];
  }
  __syncthreads();
#pragma unroll
  for (int i = 0; i < 16; ++i) {
    int r = lr + i * 4;  // row of transposed tile (= col of in)
    out[(size_t)(rowOff + c0 + r) * K + r0 + lc] = f2bf(t[lc][r]);
  }
}

__global__ void k_bias_concat(const float* __restrict__ bq, const float* __restrict__ bk,
                              const float* __restrict__ bv, float* __restrict__ out) {
  int i = blockIdx.x * 256 + threadIdx.x;
  if (i < NQKV) out[i] = (i < 2048) ? bq[i] : (i < NQK ? bk[i - 2048] : bv[i - NQK]);
}

// ---------------- GEMM: C(MxN) = A(MxK) * Bt(NxK)^T + bias ----------------
// OMODE 0: bf16 out into qkv buffer; cols >= NQK are redirected to vt[b][d][s] (transposed V)
// OMODE 1: f32 out
__device__ __forceinline__ void stage_tile(const u16* __restrict__ G, int ldg, int row0, int kt,
                                           u16* lbase, int wid, int lane) {
#pragma unroll
  for (int i = 0; i < 4; ++i) {
    int c   = (wid * 4 + i) * 64 + lane;
    int row = c >> 3, cin = c & 7;
    int cs  = cin ^ (row & 7);  // source pre-swizzle so swizzled reads see linear data (rule #21)
    const u16* g = G + (size_t)(row0 + row) * ldg + kt * 64 + cs * 8;
    gload16(g, (char*)lbase + (wid * 4 + i) * 1024);
  }
}

template <int OMODE>
__global__ __launch_bounds__(256)
void k_gemm(const u16* __restrict__ A, const u16* __restrict__ Bt,
            const float* __restrict__ bias, void* __restrict__ Cout,
            u16* __restrict__ vt, int M, int N, int K) {
  __shared__ u16 lA[2][128 * 64];
  __shared__ u16 lB[2][128 * 64];
  const int tid = threadIdx.x, lane = tid & 63, wid = tid >> 6;
  const int wm = wid >> 1, wn = wid & 1;
  const int tm = blockIdx.x, tn = blockIdx.y;
  const int nk = K >> 6;

  stage_tile(A, K, tm * 128, 0, lA[0], wid, lane);
  stage_tile(Bt, K, tn * 128, 0, lB[0], wid, lane);
  __syncthreads();

  floatx4 acc[4][4] = {};
  int buf = 0;
  for (int kt = 0; kt < nk; ++kt) {
    if (kt + 1 < nk) {
      stage_tile(A, K, tm * 128, kt + 1, lA[buf ^ 1], wid, lane);
      stage_tile(Bt, K, tn * 128, kt + 1, lB[buf ^ 1], wid, lane);
    }
    const char* pa = (const char*)&lA[buf][0];
    const char* pb = (const char*)&lB[buf][0];
#pragma unroll
    for (int kk = 0; kk < 2; ++kk) {
      bf16x8 af[4], bfr[4];
      int gch = kk * 4 + (lane >> 4);
#pragma unroll
      for (int f = 0; f < 4; ++f) {
        int ra = wm * 64 + f * 16 + (lane & 15);
        af[f]  = *(const bf16x8*)(pa + ra * 128 + ((gch ^ (ra & 7)) << 4));
        int rb = wn * 64 + f * 16 + (lane & 15);
        bfr[f] = *(const bf16x8*)(pb + rb * 128 + ((gch ^ (rb & 7)) << 4));
      }
#pragma unroll
      for (int fm = 0; fm < 4; ++fm)
#pragma unroll
        for (int fn = 0; fn < 4; ++fn)
          acc[fm][fn] = __builtin_amdgcn_mfma_f32_16x16x32_bf16(af[fm], bfr[fn], acc[fm][fn], 0, 0, 0);
    }
    __syncthreads();  // drains vmcnt (next tile staged) + all waves done reading buf
    buf ^= 1;
  }

#pragma unroll
  for (int fm = 0; fm < 4; ++fm)
#pragma unroll
    for (int fn = 0; fn < 4; ++fn)
#pragma unroll
      for (int r = 0; r < 4; ++r) {
        int rowg = tm * 128 + wm * 64 + fm * 16 + (lane >> 4) * 4 + r;
        int colg = tn * 128 + wn * 64 + fn * 16 + (lane & 15);
        float v = acc[fm][fn][r] + bias[colg];
        if constexpr (OMODE == 1) {
          ((float*)Cout)[(size_t)rowg * N + colg] = v;
        } else {
          if (colg < NQK) {
            ((u16*)Cout)[(size_t)rowg * N + colg] = f2bf(v);
          } else {  // V: store transposed vt[b][d][s]
            int d = colg - NQK;
            int bg = rowg >> 11, s = rowg & 2047;
            vt[((size_t)bg * HD + d) * S_LEN + s] = f2bf(v);
          }
        }
      }
}

// ---------------- flash attention ----------------
// grid (S/64, H, B); 4 waves, each owns 16 q-rows. KV tile = 64.
__global__ __launch_bounds__(256)
void k_attn(const u16* __restrict__ qkv, const u16* __restrict__ vt,
            const float* __restrict__ mask, u16* __restrict__ attn) {
  __shared__ u16 lK[64 * 128];     // [k][d], 256B rows, chunk-swizzled
  __shared__ u16 lV[128 * 64];     // [d][k], 128B rows, chunk-swizzled
  __shared__ u16 lP[4][16 * 64];   // per-wave P, 128B rows, chunk-swizzled
  const int tid = threadIdx.x, lane = tid & 63, wid = tid >> 6;
  const int qt = blockIdx.x, h = blockIdx.y, b = blockIdx.z;
  const int g = lane >> 4, li = lane & 15;
  const float scale = 0.08838834764831845f;  // 1/sqrt(128)

  // hoist Q fragments (A-frag: row=li, k contiguous)
  bf16x8 qf[4];
  const size_t qrow = (size_t)(b * S_LEN + qt * 64 + wid * 16 + li);
#pragma unroll
  for (int kk = 0; kk < 4; ++kk)
    qf[kk] = *(const bf16x8*)(qkv + qrow * NQKV + h * HD + kk * 32 + g * 8);

  float m_[4], l_[4];
  floatx4 acco[8] = {};
#pragma unroll
  for (int r = 0; r < 4; ++r) { m_[r] = -1e30f; l_[r] = 0.f; }

  for (int kt = 0; kt < S_LEN / 64; ++kt) {
    // stage K (64x128) and Vt (128x64), source-side chunk swizzle
#pragma unroll
    for (int i = 0; i < 4; ++i) {
      int c = (wid * 4 + i) * 64 + lane;
      {
        int row = c >> 4, cin = c & 15;
        int cs = cin ^ (row & 7);
        const u16* gk = qkv + (size_t)(b * S_LEN + kt * 64 + row) * NQKV + 2048 + cs * 8;
        gload16(gk, (char*)lK + (wid * 4 + i) * 1024);
      }
      {
        int row = c >> 3, cin = c & 7;
        int cs = cin ^ (row & 7);
        const u16* gv = vt + ((size_t)b * HD + row) * S_LEN + kt * 64 + cs * 8;
        gload16(gv, (char*)lV + (wid * 4 + i) * 1024);
      }
    }
    __syncthreads();

    // S = Q K^T  (mfma computes X*Y^T; Y = K rows)
    floatx4 accs[4] = {};
#pragma unroll
    for (int kk = 0; kk < 4; ++kk) {
      int gch = kk * 4 + g;
#pragma unroll
      for (int fn = 0; fn < 4; ++fn) {
        int rk = fn * 16 + li;
        bf16x8 kf = *(const bf16x8*)((const char*)lK + rk * 256 + ((gch ^ (rk & 7)) << 4));
        accs[fn] = __builtin_amdgcn_mfma_f32_16x16x32_bf16(qf[kk], kf, accs[fn], 0, 0, 0);
      }
    }

    // scale + mask + online softmax (rows live on 16-lane groups; 4 rows per lane)
    float p[4][4], rowm[4];
    const float* mbase = mask + (size_t)b * S_LEN * S_LEN +
                         (size_t)(qt * 64 + wid * 16 + g * 4) * S_LEN + kt * 64;
#pragma unroll
    for (int r = 0; r < 4; ++r) {
      float vmax = -1e30f;
#pragma unroll
      for (int fn = 0; fn < 4; ++fn) {
        float sv = accs[fn][r] * scale + mbase[(size_t)r * S_LEN + fn * 16 + li];
        p[fn][r] = sv;
        vmax = fmaxf(vmax, sv);
      }
      rowm[r] = vmax;
    }
#pragma unroll
    for (int off = 1; off < 16; off <<= 1)
#pragma unroll
      for (int r = 0; r < 4; ++r)
        rowm[r] = fmaxf(rowm[r], __shfl_xor(rowm[r], off, 16));

    float alpha[4], rsum[4];
#pragma unroll
    for (int r = 0; r < 4; ++r) {
      float mn = fmaxf(m_[r], rowm[r]);
      alpha[r] = __expf(m_[r] - mn);
      m_[r] = mn;
      float s = 0.f;
#pragma unroll
      for (int fn = 0; fn < 4; ++fn) {
        float pv = __expf(p[fn][r] - mn);
        p[fn][r] = pv;
        s += pv;
      }
      rsum[r] = s;
    }
#pragma unroll
    for (int off = 1; off < 16; off <<= 1)
#pragma unroll
      for (int r = 0; r < 4; ++r)
        rsum[r] += __shfl_xor(rsum[r], off, 16);
#pragma unroll
    for (int r = 0; r < 4; ++r) l_[r] = l_[r] * alpha[r] + rsum[r];
#pragma unroll
    for (int fd = 0; fd < 8; ++fd)
#pragma unroll
      for (int r = 0; r < 4; ++r) acco[fd][r] *= alpha[r];

    // P -> wave-private LDS (bf16, swizzled), then re-read as A-fragments
    u16* lPw = &lP[wid][0];
#pragma unroll
    for (int fn = 0; fn < 4; ++fn)
#pragma unroll
      for (int r = 0; r < 4; ++r) {
        int q = g * 4 + r;
        int ch = fn * 2 + (li >> 3);
        int byte_ = q * 128 + ((ch ^ (q & 7)) << 4) + ((li & 7) << 1);
        *(u16*)((char*)lPw + byte_) = f2bf(p[fn][r]);
      }
    asm volatile("s_waitcnt lgkmcnt(0)" ::: "memory");

    bf16x8 pf[2];
#pragma unroll
    for (int kk = 0; kk < 2; ++kk) {
      int ch = kk * 4 + g;
      pf[kk] = *(const bf16x8*)((const char*)lPw + li * 128 + ((ch ^ (li & 7)) << 4));
    }
    // O += P * V   (mfma X*Y^T with Y = Vt rows => exactly P@V)
#pragma unroll
    for (int fd = 0; fd < 8; ++fd)
#pragma unroll
      for (int kk = 0; kk < 2; ++kk) {
        int rd = fd * 16 + li;
        int ch = kk * 4 + g;
        bf16x8 vf = *(const bf16x8*)((const char*)lV + rd * 128 + ((ch ^ (rd & 7)) << 4));
        acco[fd] = __builtin_amdgcn_mfma_f32_16x16x32_bf16(pf[kk], vf, acco[fd], 0, 0, 0);
      }
    __syncthreads();
  }

  // epilogue: attn[b*S+s][h*HD+d] = O/l
#pragma unroll
  for (int r = 0; r < 4; ++r) {
    float inv = 1.0f / l_[r];
    size_t rowg = (size_t)(b * S_LEN + qt * 64 + wid * 16 + g * 4 + r);
#pragma unroll
    for (int fd = 0; fd < 8; ++fd)
      attn[rowg * DIMSZ + h * HD + fd * 16 + li] = f2bf(acco[fd][r] * inv);
  }
}

// ---------------- launch ----------------
extern "C" void kernel_launch(void* const* d_in, const int* in_sizes, int n_in,
                              void* d_out, int out_size, void* d_ws, size_t ws_size,
                              hipStream_t stream) {
  const float* hidden = (const float*)d_in[0];
  const float* mask   = (const float*)d_in[1];
  const float* wq = (const float*)d_in[2];
  const float* bq = (const float*)d_in[3];
  const float* wk = (const float*)d_in[4];
  const float* bk = (const float*)d_in[5];
  const float* wv = (const float*)d_in[6];
  const float* bv = (const float*)d_in[7];
  const float* wo = (const float*)d_in[8];
  const float* bo = (const float*)d_in[9];
  float* out = (float*)d_out;

  // workspace layout (total ~71.3 MB)
  char* ws = (char*)d_ws;
  u16*   hb    = (u16*)(ws);                    // hidden bf16: 4096x2048            (16.78 MB)
  u16*   wqkvT = (u16*)(ws + 16777216);         // [wq^T; wk^T; wv^T]: 2304x2048     ( 9.44 MB)
  u16*   woT   = (u16*)(ws + 26214400);         // wo^T: 2048x2048                   ( 8.39 MB)
  float* bqkv  = (float*)(ws + 34603008);       // 2304 f32
  u16*   qkv   = (u16*)(ws + 34612224);         // 4096x2304 (V cols unused)         (18.87 MB)
  u16*   vt    = (u16*)(ws + 53486592);         // 2 x 128 x 2048                    ( 1.05 MB)
  u16*   attn  = (u16*)(ws + 54535168);         // 4096x2048                         (16.78 MB)

  k_cvt_bf16<<<dim3(8192), dim3(256), 0, stream>>>(hidden, hb, 4096 * 2048 / 4);
  k_transpose_bf16<<<dim3(32, 32), dim3(256), 0, stream>>>(wq, wqkvT, 2048, 2048, 0);
  k_transpose_bf16<<<dim3(2, 32),  dim3(256), 0, stream>>>(wk, wqkvT, 2048, 128, 2048);
  k_transpose_bf16<<<dim3(2, 32),  dim3(256), 0, stream>>>(wv, wqkvT, 2048, 128, NQK);
  k_transpose_bf16<<<dim3(32, 32), dim3(256), 0, stream>>>(wo, woT, 2048, 2048, 0);
  k_bias_concat<<<dim3(9), dim3(256), 0, stream>>>(bq, bk, bv, bqkv);

  k_gemm<0><<<dim3(32, 18), dim3(256), 0, stream>>>(hb, wqkvT, bqkv, (void*)qkv, vt, 4096, NQKV, 2048);
  k_attn<<<dim3(32, 16, 2), dim3(256), 0, stream>>>(qkv, vt, mask, attn);
  k_gemm<1><<<dim3(32, 16), dim3(256), 0, stream>>>(attn, woT, bo, (void*)out, (u16*)nullptr, 4096, 2048, 2048);
}

// Round 2
// 213.279 us; speedup vs baseline: 1.4046x; 1.4046x over previous
//
#include <hip/hip_runtime.h>
#include <hip/hip_bf16.h>
#include <stdint.h>

#define S_LEN 2048
#define DIMSZ 2048
#define NH    16
#define HD    128
#define NQK   2176   // Q cols (2048) + K cols (128); V cols start here
#define NQKV  2304

typedef short  bf16x8  __attribute__((ext_vector_type(8)));
typedef float  floatx4 __attribute__((ext_vector_type(4)));
typedef float  floatx16 __attribute__((ext_vector_type(16)));
typedef int    intx4   __attribute__((ext_vector_type(4)));
typedef unsigned short u16;

#define mfma32 __builtin_amdgcn_mfma_f32_32x32x16_bf16

// round-to-nearest-even f32 -> bf16 bits
__device__ __forceinline__ u16 f2bf(float x) {
  unsigned int u = __builtin_bit_cast(unsigned int, x);
  u = (u + 0x7FFFu + ((u >> 16) & 1u)) >> 16;
  return (u16)u;
}

// v_cvt_pk_bf16_f32: word = (bf16(hi)<<16) | bf16(lo)
__device__ __forceinline__ int cvtpk(float lo, float hi) {
  int r;
  asm("v_cvt_pk_bf16_f32 %0, %1, %2" : "=v"(r) : "v"(lo), "v"(hi));
  return r;
}

// exchange: a' = [a_lo | b_lo(from lane-32)], b' = [a_hi(from lane+32) | b_hi]
__device__ __forceinline__ void half_swap(int& a, int& b, int lane) {
  int as = __shfl_xor(a, 32);
  int bs = __shfl_xor(b, 32);
  int na = (lane < 32) ? a : bs;
  int nb = (lane < 32) ? as : b;
  a = na; b = nb;
}

// async global->LDS, 16 bytes per lane; LDS dest wave-uniform base (+lane*16 by HW)
__device__ __forceinline__ void gload16(const void* g, void* l) {
  __builtin_amdgcn_global_load_lds(
      reinterpret_cast<const __attribute__((address_space(1))) void*>(reinterpret_cast<uintptr_t>(g)),
      reinterpret_cast<__attribute__((address_space(3))) void*>(reinterpret_cast<uintptr_t>(l)),
      16, 0, 0);
}

// ---------------- converts ----------------
__global__ void k_cvt_bf16(const float* __restrict__ in, u16* __restrict__ out, int n4) {
  int i = blockIdx.x * blockDim.x + threadIdx.x;
  if (i < n4) {
    float4 v = ((const float4*)in)[i];
    ushort4 o;
    o.x = f2bf(v.x); o.y = f2bf(v.y); o.z = f2bf(v.z); o.w = f2bf(v.w);
    ((ushort4*)out)[i] = o;
  }
}

// in: (K x N) f32 row-major  ->  out rows [rowOff .. rowOff+N): (N x K) bf16
__global__ void k_transpose_bf16(const float* __restrict__ in, u16* __restrict__ out,
                                 int K, int N, int rowOff) {
  __shared__ float t[64][65];
  int c0 = blockIdx.x * 64;   // N dim
  int r0 = blockIdx.y * 64;   // K dim
  int tid = threadIdx.x;
  int lr = tid >> 6;          // 0..3
  int lc = tid & 63;
#pragma unroll
  for (int i = 0; i < 16; ++i) {
    int r = lr + i * 4;
    t[r][lc] = in[(size_t)(r0 + r) * N + c0 + lc];
  }
  __syncthreads();
#pragma unroll
  for (int i = 0; i < 16; ++i) {
    int r = lr + i * 4;  // row of transposed tile (= col of in)
    out[(size_t)(rowOff + c0 + r) * K + r0 + lc] = f2bf(t[lc][r]);
  }
}

__global__ void k_bias_concat(const float* __restrict__ bq, const float* __restrict__ bk,
                              const float* __restrict__ bv, float* __restrict__ out) {
  int i = blockIdx.x * 256 + threadIdx.x;
  if (i < NQKV) out[i] = (i < 2048) ? bq[i] : (i < NQK ? bk[i - 2048] : bv[i - NQK]);
}

// ---------------- GEMM: C(MxN) = A(MxK) * Bt(NxK)^T + bias ----------------
__device__ __forceinline__ void stage_tile(const u16* __restrict__ G, int ldg, int row0, int kt,
                                           u16* lbase, int wid, int lane) {
#pragma unroll
  for (int i = 0; i < 4; ++i) {
    int c   = (wid * 4 + i) * 64 + lane;
    int row = c >> 3, cin = c & 7;
    int cs  = cin ^ (row & 7);  // source pre-swizzle (rule #21)
    const u16* g = G + (size_t)(row0 + row) * ldg + kt * 64 + cs * 8;
    gload16(g, (char*)lbase + (wid * 4 + i) * 1024);
  }
}

template <int OMODE>
__global__ __launch_bounds__(256)
void k_gemm(const u16* __restrict__ A, const u16* __restrict__ Bt,
            const float* __restrict__ bias, void* __restrict__ Cout,
            u16* __restrict__ vt, int M, int N, int K) {
  __shared__ u16 lA[2][128 * 64];
  __shared__ u16 lB[2][128 * 64];
  const int tid = threadIdx.x, lane = tid & 63, wid = tid >> 6;
  const int wm = wid >> 1, wn = wid & 1;
  const int tm = blockIdx.x, tn = blockIdx.y;
  const int nk = K >> 6;

  stage_tile(A, K, tm * 128, 0, lA[0], wid, lane);
  stage_tile(Bt, K, tn * 128, 0, lB[0], wid, lane);
  __syncthreads();

  floatx4 acc[4][4] = {};
  int buf = 0;
  for (int kt = 0; kt < nk; ++kt) {
    if (kt + 1 < nk) {
      stage_tile(A, K, tm * 128, kt + 1, lA[buf ^ 1], wid, lane);
      stage_tile(Bt, K, tn * 128, kt + 1, lB[buf ^ 1], wid, lane);
    }
    const char* pa = (const char*)&lA[buf][0];
    const char* pb = (const char*)&lB[buf][0];
#pragma unroll
    for (int kk = 0; kk < 2; ++kk) {
      bf16x8 af[4], bfr[4];
      int gch = kk * 4 + (lane >> 4);
#pragma unroll
      for (int f = 0; f < 4; ++f) {
        int ra = wm * 64 + f * 16 + (lane & 15);
        af[f]  = *(const bf16x8*)(pa + ra * 128 + ((gch ^ (ra & 7)) << 4));
        int rb = wn * 64 + f * 16 + (lane & 15);
        bfr[f] = *(const bf16x8*)(pb + rb * 128 + ((gch ^ (rb & 7)) << 4));
      }
#pragma unroll
      for (int fm = 0; fm < 4; ++fm)
#pragma unroll
        for (int fn = 0; fn < 4; ++fn)
          acc[fm][fn] = __builtin_amdgcn_mfma_f32_16x16x32_bf16(af[fm], bfr[fn], acc[fm][fn], 0, 0, 0);
    }
    __syncthreads();
    buf ^= 1;
  }

#pragma unroll
  for (int fm = 0; fm < 4; ++fm)
#pragma unroll
    for (int fn = 0; fn < 4; ++fn)
#pragma unroll
      for (int r = 0; r < 4; ++r) {
        int rowg = tm * 128 + wm * 64 + fm * 16 + (lane >> 4) * 4 + r;
        int colg = tn * 128 + wn * 64 + fn * 16 + (lane & 15);
        float v = acc[fm][fn][r] + bias[colg];
        if constexpr (OMODE == 1) {
          ((float*)Cout)[(size_t)rowg * N + colg] = v;
        } else {
          if (colg < NQK) {
            ((u16*)Cout)[(size_t)rowg * N + colg] = f2bf(v);
          } else {  // V: store transposed vt[b][d][s]
            int d = colg - NQK;
            int bg = rowg >> 11, s = rowg & 2047;
            vt[((size_t)bg * HD + d) * S_LEN + s] = f2bf(v);
          }
        }
      }
}

// ---------------- flash attention (8-wave, swapped-operand, MQA-shared K/V/mask) ----
// grid (S/32, 2, B); 512 threads = 8 waves; wave w = head hg*8+w, all on same 32 q-rows.
__device__ __forceinline__ void stage_kv(const u16* __restrict__ qkv, const u16* __restrict__ vt,
                                         int b, int kt, u16* lK, u16* lV, int wid, int lane) {
#pragma unroll
  for (int i = 0; i < 2; ++i) {
    int seg = wid * 2 + i;
    {  // K tile: 64 rows x 256B (16 chunks), slot cin holds logical cin^(r&7)
      int r = seg * 4 + (lane >> 4), cin = lane & 15;
      const u16* g = qkv + (size_t)(b * S_LEN + kt * 64 + r) * NQKV + 2048 + ((cin ^ (r & 7)) * 8);
      gload16(g, (char*)lK + seg * 1024);
    }
    {  // Vt tile: 128 rows x 128B (8 chunks)
      int r = seg * 8 + (lane >> 3), cin = lane & 7;
      const u16* g = vt + ((size_t)b * HD + r) * S_LEN + kt * 64 + ((cin ^ (r & 7)) * 8);
      gload16(g, (char*)lV + seg * 1024);
    }
  }
}

__global__ __launch_bounds__(512)
void k_attn(const u16* __restrict__ qkv, const u16* __restrict__ vt,
            const float* __restrict__ mask, u16* __restrict__ attn) {
  __shared__ __align__(16) u16   lK[2][64 * 128];
  __shared__ __align__(16) u16   lV[2][128 * 64];
  __shared__ __align__(16) float lM[2][32 * 64];
  const int tid = threadIdx.x, lane = tid & 63, wid = tid >> 6;
  const int qt = blockIdx.x, hg = blockIdx.y, b = blockIdx.z;
  const int h = hg * 8 + wid;
  const int q = lane & 31, h5 = lane >> 5;
  const float scale = 0.08838834764831845f;  // 1/sqrt(128)

  // hoist Q (B-frag: col=q, d = cs*16 + h5*8 + idx)
  bf16x8 qf[8];
  const size_t qrow = (size_t)(b * S_LEN + qt * 32 + q);
#pragma unroll
  for (int cs = 0; cs < 8; ++cs)
    qf[cs] = *(const bf16x8*)(qkv + qrow * NQKV + h * HD + cs * 16 + h5 * 8);

  float m_ = -1e30f, l_ = 0.f;
  floatx16 acco[4] = {};  // O^T: col=q (lane-local), row = d

  // mask stage helpers
  const int mq = tid >> 4, mc = tid & 15;
  const float* mrow = mask + (size_t)b * S_LEN * S_LEN + (size_t)(qt * 32 + mq) * S_LEN + mc * 4;

  // prologue: stage kt=0
  stage_kv(qkv, vt, b, 0, lK[0], lV[0], wid, lane);
  floatx4 mreg = *(const floatx4*)(mrow);
  *(floatx4*)((char*)&lM[0][0] + mq * 256 + ((mc ^ (mq & 7)) << 4)) = mreg;
  __syncthreads();

  int buf = 0;
  for (int kt = 0; kt < S_LEN / 64; ++kt) {
    if (kt + 1 < S_LEN / 64) {
      stage_kv(qkv, vt, b, kt + 1, lK[buf ^ 1], lV[buf ^ 1], wid, lane);
      mreg = *(const floatx4*)(mrow + (size_t)(kt + 1) * 64);
    }

    // ---- QK^T swapped: accs = K * Q^T = S^T (col = q = lane&31) ----
    floatx16 accs0 = {}, accs1 = {};
    const char* pK = (const char*)&lK[buf][0];
#pragma unroll
    for (int cs = 0; cs < 8; ++cs) {
      int c = cs * 2 + h5;
      bf16x8 kf0 = *(const bf16x8*)(pK + q * 256 + ((c ^ (q & 7)) << 4));
      bf16x8 kf1 = *(const bf16x8*)(pK + (32 + q) * 256 + 8192 - 8192 + ((c ^ (q & 7)) << 4));
      accs0 = mfma32(kf0, qf[cs], accs0, 0, 0, 0);
      accs1 = mfma32(kf1, qf[cs], accs1, 0, 0, 0);
    }

    // ---- online softmax, fully in-register (k local: (j&3)+8*(j>>2)+4*h5 +32*kb) ----
    float pr[32];
    float rowm = -1e30f;
    const char* pM = (const char*)&lM[buf][0];
#pragma unroll
    for (int kb = 0; kb < 2; ++kb)
#pragma unroll
      for (int rg = 0; rg < 4; ++rg) {
        int c = kb * 8 + rg * 2 + h5;
        floatx4 m4 = *(const floatx4*)(pM + q * 256 + ((c ^ (q & 7)) << 4));
#pragma unroll
        for (int t = 0; t < 4; ++t) {
          float sv = (kb ? accs1[rg * 4 + t] : accs0[rg * 4 + t]) * scale + m4[t];
          pr[kb * 16 + rg * 4 + t] = sv;
          rowm = fmaxf(rowm, sv);
        }
      }
    rowm = fmaxf(rowm, __shfl_xor(rowm, 32));
    float mn = fmaxf(m_, rowm);
    float al = __expf(m_ - mn);
    m_ = mn;
    float sum = 0.f;
#pragma unroll
    for (int j = 0; j < 32; ++j) {
      float e = __expf(pr[j] - mn);
      pr[j] = e;
      sum += e;
    }
    sum += __shfl_xor(sum, 32);
    l_ = l_ * al + sum;
#pragma unroll
    for (int dt = 0; dt < 4; ++dt) acco[dt] *= al;

    // ---- pack P into PV B-fragments (cvt_pk + half swap, no LDS) ----
    bf16x8 pf[4];
#pragma unroll
    for (int kb = 0; kb < 2; ++kb)
#pragma unroll
      for (int s = 0; s < 2; ++s) {
        int base = kb * 16 + s * 8;
        int A0 = cvtpk(pr[base + 0], pr[base + 1]);
        int A1 = cvtpk(pr[base + 2], pr[base + 3]);
        int B0 = cvtpk(pr[base + 4], pr[base + 5]);
        int B1 = cvtpk(pr[base + 6], pr[base + 7]);
        half_swap(A0, B0, lane);
        half_swap(A1, B1, lane);
        intx4 w;
        w[0] = A0; w[1] = A1; w[2] = B0; w[3] = B1;
        pf[kb * 2 + s] = __builtin_bit_cast(bf16x8, w);
      }

    // ---- PV swapped: acco += Vt * P^T = O^T (col = q) ----
    const char* pV = (const char*)&lV[buf][0];
#pragma unroll
    for (int dt = 0; dt < 4; ++dt) {
      int rd = dt * 32 + q;
#pragma unroll
      for (int ks = 0; ks < 4; ++ks) {
        int c = ks * 2 + h5;
        bf16x8 vf = *(const bf16x8*)(pV + rd * 128 + ((c ^ (q & 7)) << 4));
        acco[dt] = mfma32(vf, pf[ks], acco[dt], 0, 0, 0);
      }
    }

    if (kt + 1 < S_LEN / 64)
      *(floatx4*)((char*)&lM[buf ^ 1][0] + mq * 256 + ((mc ^ (mq & 7)) << 4)) = mreg;
    __syncthreads();
    buf ^= 1;
  }

  // ---- epilogue: attn[q][h*HD + d] = O/l ----
  float inv = 1.0f / l_;
  u16* obase = attn + qrow * DIMSZ + h * HD;
#pragma unroll
  for (int dt = 0; dt < 4; ++dt)
#pragma unroll
    for (int rg = 0; rg < 4; ++rg) {
      int d0 = dt * 32 + rg * 8 + h5 * 4;
      ushort4 st;
      st.x = f2bf(acco[dt][rg * 4 + 0] * inv);
      st.y = f2bf(acco[dt][rg * 4 + 1] * inv);
      st.z = f2bf(acco[dt][rg * 4 + 2] * inv);
      st.w = f2bf(acco[dt][rg * 4 + 3] * inv);
      *(ushort4*)(obase + d0) = st;
    }
}

// ---------------- launch ----------------
extern "C" void kernel_launch(void* const* d_in, const int* in_sizes, int n_in,
                              void* d_out, int out_size, void* d_ws, size_t ws_size,
                              hipStream_t stream) {
  const float* hidden = (const float*)d_in[0];
  const float* mask   = (const float*)d_in[1];
  const float* wq = (const float*)d_in[2];
  const float* bq = (const float*)d_in[3];
  const float* wk = (const float*)d_in[4];
  const float* bk = (const float*)d_in[5];
  const float* wv = (const float*)d_in[6];
  const float* bv = (const float*)d_in[7];
  const float* wo = (const float*)d_in[8];
  const float* bo = (const float*)d_in[9];
  float* out = (float*)d_out;

  // workspace layout (total ~71.3 MB)
  char* ws = (char*)d_ws;
  u16*   hb    = (u16*)(ws);                    // hidden bf16: 4096x2048
  u16*   wqkvT = (u16*)(ws + 16777216);         // [wq^T; wk^T; wv^T]: 2304x2048
  u16*   woT   = (u16*)(ws + 26214400);         // wo^T: 2048x2048
  float* bqkv  = (float*)(ws + 34603008);       // 2304 f32
  u16*   qkv   = (u16*)(ws + 34612224);         // 4096x2304
  u16*   vt    = (u16*)(ws + 53486592);         // 2 x 128 x 2048
  u16*   attn  = (u16*)(ws + 54535168);         // 4096x2048

  k_cvt_bf16<<<dim3(8192), dim3(256), 0, stream>>>(hidden, hb, 4096 * 2048 / 4);
  k_transpose_bf16<<<dim3(32, 32), dim3(256), 0, stream>>>(wq, wqkvT, 2048, 2048, 0);
  k_transpose_bf16<<<dim3(2, 32),  dim3(256), 0, stream>>>(wk, wqkvT, 2048, 128, 2048);
  k_transpose_bf16<<<dim3(2, 32),  dim3(256), 0, stream>>>(wv, wqkvT, 2048, 128, NQK);
  k_transpose_bf16<<<dim3(32, 32), dim3(256), 0, stream>>>(wo, woT, 2048, 2048, 0);
  k_bias_concat<<<dim3(9), dim3(256), 0, stream>>>(bq, bk, bv, bqkv);

  k_gemm<0><<<dim3(32, 18), dim3(256), 0, stream>>>(hb, wqkvT, bqkv, (void*)qkv, vt, 4096, NQKV, 2048);
  k_attn<<<dim3(64, 2, 2), dim3(512), 0, stream>>>(qkv, vt, mask, attn);
  k_gemm<1><<<dim3(32, 16), dim3(256), 0, stream>>>(attn, woT, bo, (void*)out, (u16*)nullptr, 4096, 2048, 2048);
}

// Round 4
// 204.748 us; speedup vs baseline: 1.4631x; 1.0417x over previous
//
#include <hip/hip_runtime.h>
#include <hip/hip_bf16.h>
#include <stdint.h>

#define S_LEN 2048
#define DIMSZ 2048
#define NH    16
#define HD    128
#define NQK   2176   // Q cols (2048) + K cols (128); V cols start here
#define NQKV  2304

typedef short  bf16x8  __attribute__((ext_vector_type(8)));
typedef float  floatx4 __attribute__((ext_vector_type(4)));
typedef float  floatx16 __attribute__((ext_vector_type(16)));
typedef int    intx4   __attribute__((ext_vector_type(4)));
typedef unsigned short u16;

#define mfma32 __builtin_amdgcn_mfma_f32_32x32x16_bf16
#define LOG2E 1.4426950408889634f

// round-to-nearest-even f32 -> bf16 bits
__device__ __forceinline__ u16 f2bf(float x) {
  unsigned int u = __builtin_bit_cast(unsigned int, x);
  u = (u + 0x7FFFu + ((u >> 16) & 1u)) >> 16;
  return (u16)u;
}

// v_cvt_pk_bf16_f32: word = (bf16(hi)<<16) | bf16(lo)   (plain VALU, no hazard)
__device__ __forceinline__ int cvtpk(float lo, float hi) {
  int r;
  asm("v_cvt_pk_bf16_f32 %0, %1, %2" : "=v"(r) : "v"(lo), "v"(hi));
  return r;
}

// 2^x — use the builtin so the compiler handles the TRANS wait-state hazard
#if __has_builtin(__builtin_amdgcn_exp2f)
__device__ __forceinline__ float fexp2(float x) { return __builtin_amdgcn_exp2f(x); }
#else
__device__ __forceinline__ float fexp2(float x) { return exp2f(x); }
#endif

// half swap via the BUILTIN (hazard-modeled): a'[32:63]=b[0:31], b'[0:31]=a[32:63]
#if __has_builtin(__builtin_amdgcn_permlane32_swap)
__device__ __forceinline__ void half_swap(int& a, int& b) {
  auto r = __builtin_amdgcn_permlane32_swap(a, b, false, false);
  a = (int)r[0]; b = (int)r[1];
}
__device__ __forceinline__ float red_max32(float x) {
  int xi = __builtin_bit_cast(int, x);
  auto r = __builtin_amdgcn_permlane32_swap(xi, xi, false, false);
  return fmaxf(__builtin_bit_cast(float, (int)r[0]), __builtin_bit_cast(float, (int)r[1]));
}
__device__ __forceinline__ float red_add32(float x) {
  int xi = __builtin_bit_cast(int, x);
  auto r = __builtin_amdgcn_permlane32_swap(xi, xi, false, false);
  return __builtin_bit_cast(float, (int)r[0]) + __builtin_bit_cast(float, (int)r[1]);
}
#else
__device__ __forceinline__ void half_swap(int& a, int& b) {
  int as = __shfl_xor(a, 32);
  int bs = __shfl_xor(b, 32);
  int lane = threadIdx.x & 63;
  int na = (lane < 32) ? a : bs;
  int nb = (lane < 32) ? as : b;
  a = na; b = nb;
}
__device__ __forceinline__ float red_max32(float x) { return fmaxf(x, __shfl_xor(x, 32)); }
__device__ __forceinline__ float red_add32(float x) { return x + __shfl_xor(x, 32); }
#endif

// async global->LDS, 16 bytes per lane; LDS dest wave-uniform base (+lane*16 by HW)
__device__ __forceinline__ void gload16(const void* g, void* l) {
  __builtin_amdgcn_global_load_lds(
      reinterpret_cast<const __attribute__((address_space(1))) void*>(reinterpret_cast<uintptr_t>(g)),
      reinterpret_cast<__attribute__((address_space(3))) void*>(reinterpret_cast<uintptr_t>(l)),
      16, 0, 0);
}

// ---------------- converts ----------------
__global__ void k_cvt_bf16(const float* __restrict__ in, u16* __restrict__ out, int n4) {
  int i = blockIdx.x * blockDim.x + threadIdx.x;
  if (i < n4) {
    float4 v = ((const float4*)in)[i];
    ushort4 o;
    o.x = f2bf(v.x); o.y = f2bf(v.y); o.z = f2bf(v.z); o.w = f2bf(v.w);
    ((ushort4*)out)[i] = o;
  }
}

// in: (K x N) f32 row-major  ->  out rows [rowOff .. rowOff+N): (N x K) bf16
__global__ void k_transpose_bf16(const float* __restrict__ in, u16* __restrict__ out,
                                 int K, int N, int rowOff) {
  __shared__ float t[64][65];
  int c0 = blockIdx.x * 64;   // N dim
  int r0 = blockIdx.y * 64;   // K dim
  int tid = threadIdx.x;
  int lr = tid >> 6;          // 0..3
  int lc = tid & 63;
#pragma unroll
  for (int i = 0; i < 16; ++i) {
    int r = lr + i * 4;
    t[r][lc] = in[(size_t)(r0 + r) * N + c0 + lc];
  }
  __syncthreads();
#pragma unroll
  for (int i = 0; i < 16; ++i) {
    int r = lr + i * 4;  // row of transposed tile (= col of in)
    out[(size_t)(rowOff + c0 + r) * K + r0 + lc] = f2bf(t[lc][r]);
  }
}

__global__ void k_bias_concat(const float* __restrict__ bq, const float* __restrict__ bk,
                              const float* __restrict__ bv, float* __restrict__ out) {
  int i = blockIdx.x * 256 + threadIdx.x;
  if (i < NQKV) out[i] = (i < 2048) ? bq[i] : (i < NQK ? bk[i - 2048] : bv[i - NQK]);
}

// ---------------- GEMM: C(MxN) = A(MxK) * Bt(NxK)^T + bias ----------------
__device__ __forceinline__ void stage_tile(const u16* __restrict__ G, int ldg, int row0, int kt,
                                           u16* lbase, int wid, int lane) {
#pragma unroll
  for (int i = 0; i < 4; ++i) {
    int c   = (wid * 4 + i) * 64 + lane;
    int row = c >> 3, cin = c & 7;
    int cs  = cin ^ (row & 7);  // source pre-swizzle (rule #21)
    const u16* g = G + (size_t)(row0 + row) * ldg + kt * 64 + cs * 8;
    gload16(g, (char*)lbase + (wid * 4 + i) * 1024);
  }
}

template <int OMODE>
__global__ __launch_bounds__(256)
void k_gemm(const u16* __restrict__ A, const u16* __restrict__ Bt,
            const float* __restrict__ bias, void* __restrict__ Cout,
            u16* __restrict__ vt, int M, int N, int K) {
  __shared__ u16 lA[2][128 * 64];
  __shared__ u16 lB[2][128 * 64];
  const int tid = threadIdx.x, lane = tid & 63, wid = tid >> 6;
  const int wm = wid >> 1, wn = wid & 1;
  const int tm = blockIdx.x, tn = blockIdx.y;
  const int nk = K >> 6;

  stage_tile(A, K, tm * 128, 0, lA[0], wid, lane);
  stage_tile(Bt, K, tn * 128, 0, lB[0], wid, lane);
  __syncthreads();

  floatx4 acc[4][4] = {};
  int buf = 0;
  for (int kt = 0; kt < nk; ++kt) {
    if (kt + 1 < nk) {
      stage_tile(A, K, tm * 128, kt + 1, lA[buf ^ 1], wid, lane);
      stage_tile(Bt, K, tn * 128, kt + 1, lB[buf ^ 1], wid, lane);
    }
    const char* pa = (const char*)&lA[buf][0];
    const char* pb = (const char*)&lB[buf][0];
#pragma unroll
    for (int kk = 0; kk < 2; ++kk) {
      bf16x8 af[4], bfr[4];
      int gch = kk * 4 + (lane >> 4);
#pragma unroll
      for (int f = 0; f < 4; ++f) {
        int ra = wm * 64 + f * 16 + (lane & 15);
        af[f]  = *(const bf16x8*)(pa + ra * 128 + ((gch ^ (ra & 7)) << 4));
        int rb = wn * 64 + f * 16 + (lane & 15);
        bfr[f] = *(const bf16x8*)(pb + rb * 128 + ((gch ^ (rb & 7)) << 4));
      }
      __builtin_amdgcn_s_setprio(1);
#pragma unroll
      for (int fm = 0; fm < 4; ++fm)
#pragma unroll
        for (int fn = 0; fn < 4; ++fn)
          acc[fm][fn] = __builtin_amdgcn_mfma_f32_16x16x32_bf16(af[fm], bfr[fn], acc[fm][fn], 0, 0, 0);
      __builtin_amdgcn_s_setprio(0);
    }
    __syncthreads();
    buf ^= 1;
  }

#pragma unroll
  for (int fm = 0; fm < 4; ++fm)
#pragma unroll
    for (int fn = 0; fn < 4; ++fn)
#pragma unroll
      for (int r = 0; r < 4; ++r) {
        int rowg = tm * 128 + wm * 64 + fm * 16 + (lane >> 4) * 4 + r;
        int colg = tn * 128 + wn * 64 + fn * 16 + (lane & 15);
        float v = acc[fm][fn][r] + bias[colg];
        if constexpr (OMODE == 1) {
          ((float*)Cout)[(size_t)rowg * N + colg] = v;
        } else {
          if (colg < NQK) {
            ((u16*)Cout)[(size_t)rowg * N + colg] = f2bf(v);
          } else {  // V: store transposed vt[b][d][s]
            int d = colg - NQK;
            int bg = rowg >> 11, s = rowg & 2047;
            vt[((size_t)bg * HD + d) * S_LEN + s] = f2bf(v);
          }
        }
      }
}

// ---------------- flash attention (8-wave, swapped-operand, MQA-shared K/V/mask) ----
// grid (S/32, 2, B); 512 threads = 8 waves; wave w = head hg*8+w, all on same 32 q-rows.
__device__ __forceinline__ void stage_kv(const u16* __restrict__ qkv, const u16* __restrict__ vt,
                                         int b, int kt, u16* lK, u16* lV, int wid, int lane) {
#pragma unroll
  for (int i = 0; i < 2; ++i) {
    int seg = wid * 2 + i;
    {  // K tile: 64 rows x 256B (16 chunks), slot cin holds logical cin^(r&7)
      int r = seg * 4 + (lane >> 4), cin = lane & 15;
      const u16* g = qkv + (size_t)(b * S_LEN + kt * 64 + r) * NQKV + 2048 + ((cin ^ (r & 7)) * 8);
      gload16(g, (char*)lK + seg * 1024);
    }
    {  // Vt tile: 128 rows x 128B (8 chunks)
      int r = seg * 8 + (lane >> 3), cin = lane & 7;
      const u16* g = vt + ((size_t)b * HD + r) * S_LEN + kt * 64 + ((cin ^ (r & 7)) * 8);
      gload16(g, (char*)lV + seg * 1024);
    }
  }
}

__global__ __launch_bounds__(512)
void k_attn(const u16* __restrict__ qkv, const u16* __restrict__ vt,
            const float* __restrict__ mask, u16* __restrict__ attn) {
  __shared__ __align__(16) u16   lK[2][64 * 128];
  __shared__ __align__(16) u16   lV[2][128 * 64];
  __shared__ __align__(16) float lM[2][32 * 64];   // mask pre-scaled by log2e
  const int tid = threadIdx.x, lane = tid & 63, wid = tid >> 6;
  const int qt = blockIdx.x, hg = blockIdx.y, b = blockIdx.z;
  const int h = hg * 8 + wid;
  const int q = lane & 31, h5 = lane >> 5;
  const float c_sl2 = 0.08838834764831845f * LOG2E;  // scale * log2(e)

  // hoist Q (B-frag: col=q, d = cs*16 + h5*8 + idx)
  bf16x8 qf[8];
  const size_t qrow = (size_t)(b * S_LEN + qt * 32 + q);
#pragma unroll
  for (int cs = 0; cs < 8; ++cs)
    qf[cs] = *(const bf16x8*)(qkv + qrow * NQKV + h * HD + cs * 16 + h5 * 8);

  float m_ = -1e30f, l_ = 0.f;
  floatx16 acco[4] = {};  // O^T: col=q (lane-local), row = d

  // mask stage helpers
  const int mq = tid >> 4, mc = tid & 15;
  const float* mrow = mask + (size_t)b * S_LEN * S_LEN + (size_t)(qt * 32 + mq) * S_LEN + mc * 4;

  // prologue: stage kt=0
  stage_kv(qkv, vt, b, 0, lK[0], lV[0], wid, lane);
  floatx4 mreg = *(const floatx4*)(mrow);
  *(floatx4*)((char*)&lM[0][0] + mq * 256 + ((mc ^ (mq & 7)) << 4)) = mreg * LOG2E;
  __syncthreads();

  int buf = 0;
  for (int kt = 0; kt < S_LEN / 64; ++kt) {
    if (kt + 1 < S_LEN / 64) {
      stage_kv(qkv, vt, b, kt + 1, lK[buf ^ 1], lV[buf ^ 1], wid, lane);
      mreg = *(const floatx4*)(mrow + (size_t)(kt + 1) * 64);
    }

    // ---- QK^T swapped: accs = K * Q^T = S^T (col = q = lane&31) ----
    floatx16 accs0 = {}, accs1 = {};
    const char* pK = (const char*)&lK[buf][0];
    __builtin_amdgcn_s_setprio(1);
#pragma unroll
    for (int cs = 0; cs < 8; ++cs) {
      int c = cs * 2 + h5;
      bf16x8 kf0 = *(const bf16x8*)(pK + q * 256 + ((c ^ (q & 7)) << 4));
      bf16x8 kf1 = *(const bf16x8*)(pK + (32 + q) * 256 + ((c ^ (q & 7)) << 4));
      accs0 = mfma32(kf0, qf[cs], accs0, 0, 0, 0);
      accs1 = mfma32(kf1, qf[cs], accs1, 0, 0, 0);
    }
    __builtin_amdgcn_s_setprio(0);

    // ---- online softmax, log2 domain, fully in-register ----
    float pr[32];
    float rowm = -1e30f;
    const char* pM = (const char*)&lM[buf][0];
#pragma unroll
    for (int kb = 0; kb < 2; ++kb)
#pragma unroll
      for (int rg = 0; rg < 4; ++rg) {
        int c = kb * 8 + rg * 2 + h5;
        floatx4 m4 = *(const floatx4*)(pM + q * 256 + ((c ^ (q & 7)) << 4));
#pragma unroll
        for (int t = 0; t < 4; ++t) {
          float sv = (kb ? accs1[rg * 4 + t] : accs0[rg * 4 + t]) * c_sl2 + m4[t];
          pr[kb * 16 + rg * 4 + t] = sv;
          rowm = fmaxf(rowm, sv);
        }
      }
    rowm = red_max32(rowm);
    // defer-max (T13): only rescale when max grows by > 8/ln2 (in log2 units)
    if (__any(rowm > m_ + 11.5415603f)) {
      float mn = fmaxf(m_, rowm);
      float al = fexp2(m_ - mn);
      m_ = mn;
      l_ *= al;
#pragma unroll
      for (int dt = 0; dt < 4; ++dt) acco[dt] *= al;
    }
    float sum = 0.f;
#pragma unroll
    for (int j = 0; j < 32; ++j) {
      float e = fexp2(pr[j] - m_);
      pr[j] = e;
      sum += e;
    }
    l_ += red_add32(sum);

    // ---- pack P into PV B-fragments (cvt_pk + permlane32_swap, no LDS/DS) ----
    bf16x8 pf[4];
#pragma unroll
    for (int kb = 0; kb < 2; ++kb)
#pragma unroll
      for (int s = 0; s < 2; ++s) {
        int base = kb * 16 + s * 8;
        int A0 = cvtpk(pr[base + 0], pr[base + 1]);
        int A1 = cvtpk(pr[base + 2], pr[base + 3]);
        int B0 = cvtpk(pr[base + 4], pr[base + 5]);
        int B1 = cvtpk(pr[base + 6], pr[base + 7]);
        half_swap(A0, B0);
        half_swap(A1, B1);
        intx4 w;
        w[0] = A0; w[1] = A1; w[2] = B0; w[3] = B1;
        pf[kb * 2 + s] = __builtin_bit_cast(bf16x8, w);
      }

    // ---- PV swapped: acco += Vt * P^T = O^T (col = q) ----
    const char* pV = (const char*)&lV[buf][0];
    __builtin_amdgcn_s_setprio(1);
#pragma unroll
    for (int dt = 0; dt < 4; ++dt) {
      int rd = dt * 32 + q;
#pragma unroll
      for (int ks = 0; ks < 4; ++ks) {
        int c = ks * 2 + h5;
        bf16x8 vf = *(const bf16x8*)(pV + rd * 128 + ((c ^ (q & 7)) << 4));
        acco[dt] = mfma32(vf, pf[ks], acco[dt], 0, 0, 0);
      }
    }
    __builtin_amdgcn_s_setprio(0);

    if (kt + 1 < S_LEN / 64)
      *(floatx4*)((char*)&lM[buf ^ 1][0] + mq * 256 + ((mc ^ (mq & 7)) << 4)) = mreg * LOG2E;
    __syncthreads();
    buf ^= 1;
  }

  // ---- epilogue: attn[q][h*HD + d] = O/l ----
  float inv = 1.0f / l_;
  u16* obase = attn + qrow * DIMSZ + h * HD;
#pragma unroll
  for (int dt = 0; dt < 4; ++dt)
#pragma unroll
    for (int rg = 0; rg < 4; ++rg) {
      int d0 = dt * 32 + rg * 8 + h5 * 4;
      ushort4 st;
      st.x = f2bf(acco[dt][rg * 4 + 0] * inv);
      st.y = f2bf(acco[dt][rg * 4 + 1] * inv);
      st.z = f2bf(acco[dt][rg * 4 + 2] * inv);
      st.w = f2bf(acco[dt][rg * 4 + 3] * inv);
      *(ushort4*)(obase + d0) = st;
    }
}

// ---------------- launch ----------------
extern "C" void kernel_launch(void* const* d_in, const int* in_sizes, int n_in,
                              void* d_out, int out_size, void* d_ws, size_t ws_size,
                              hipStream_t stream) {
  const float* hidden = (const float*)d_in[0];
  const float* mask   = (const float*)d_in[1];
  const float* wq = (const float*)d_in[2];
  const float* bq = (const float*)d_in[3];
  const float* wk = (const float*)d_in[4];
  const float* bk = (const float*)d_in[5];
  const float* wv = (const float*)d_in[6];
  const float* bv = (const float*)d_in[7];
  const float* wo = (const float*)d_in[8];
  const float* bo = (const float*)d_in[9];
  float* out = (float*)d_out;

  // workspace layout (total ~71.3 MB)
  char* ws = (char*)d_ws;
  u16*   hb    = (u16*)(ws);                    // hidden bf16: 4096x2048
  u16*   wqkvT = (u16*)(ws + 16777216);         // [wq^T; wk^T; wv^T]: 2304x2048
  u16*   woT   = (u16*)(ws + 26214400);         // wo^T: 2048x2048
  float* bqkv  = (float*)(ws + 34603008);       // 2304 f32
  u16*   qkv   = (u16*)(ws + 34612224);         // 4096x2304
  u16*   vt    = (u16*)(ws + 53486592);         // 2 x 128 x 2048
  u16*   attn  = (u16*)(ws + 54535168);         // 4096x2048

  k_cvt_bf16<<<dim3(8192), dim3(256), 0, stream>>>(hidden, hb, 4096 * 2048 / 4);
  k_transpose_bf16<<<dim3(32, 32), dim3(256), 0, stream>>>(wq, wqkvT, 2048, 2048, 0);
  k_transpose_bf16<<<dim3(2, 32),  dim3(256), 0, stream>>>(wk, wqkvT, 2048, 128, 2048);
  k_transpose_bf16<<<dim3(2, 32),  dim3(256), 0, stream>>>(wv, wqkvT, 2048, 128, NQK);
  k_transpose_bf16<<<dim3(32, 32), dim3(256), 0, stream>>>(wo, woT, 2048, 2048, 0);
  k_bias_concat<<<dim3(9), dim3(256), 0, stream>>>(bq, bk, bv, bqkv);

  k_gemm<0><<<dim3(32, 18), dim3(256), 0, stream>>>(hb, wqkvT, bqkv, (void*)qkv, vt, 4096, NQKV, 2048);
  k_attn<<<dim3(64, 2, 2), dim3(512), 0, stream>>>(qkv, vt, mask, attn);
  k_gemm<1><<<dim3(32, 16), dim3(256), 0, stream>>>(attn, woT, bo, (void*)out, (u16*)nullptr, 4096, 2048, 2048);
}